// Round 8
// baseline (242.426 us; speedup 1.0000x reference)
//
#include <hip/hip_runtime.h>
#include <math.h>

// ConvCaps EM routing, fp32 I/O. n=392 positions, one 512-thread block each.
// R8 = R6 (proven 113us) + 2-way k-iteration interleave in sweeps 1-2:
// the softmax over c is a ~12-deep dependent shuffle/exp chain per k-iter;
// successive k-iters are independent, so processing kA and kB=kA+16 with
// explicitly interleaved chains hides shuffle latency under VALU work.
// launch_bounds(512,4): 128-VGPR cap, guarantees 2 blocks (16 waves)/CU
// (R7 lesson: doubling ACCUMULATOR state per thread kills scheduling; this
// doubles only transient state).

#define NTH 512
#define KK 288
#define KT 18         // 288 / 16 k-groups
#define CC 32
#define PS 16
#define EPSF 1e-8f
#define LAMF 1e-3f
#define HL2PI 0.91893853320467274178f   // 0.5*ln(2*pi)

__device__ __forceinline__ float4 ld4(const float* p){ return *(const float4*)p; }
__device__ __forceinline__ float rcpf(float x){ return __builtin_amdgcn_rcpf(x); }

extern "C" __global__ void __launch_bounds__(NTH, 4)
convcaps_em_kernel(const float* __restrict__ x, const float* __restrict__ wgt,
                   const float* __restrict__ beta_a, const float* __restrict__ beta_u,
                   float* __restrict__ out)
{
  __shared__ float sP[KK*PS];        // poses, xor-swizzled groups (18432 B)
  __shared__ float sA[KK];           // f = a/(a+eps) (1152 B)
  __shared__ float sPart[8*CC*33];   // wave partials t0|t1[16]|t2[16] (33792 B)
  __shared__ float sMu[CC*17];       // (2176 B)
  __shared__ float sNI2[CC*17];      // -0.5/sigma^2 (2176 B)
  __shared__ float sLs[CC], sLnA[CC], sAo[CC];   // 384 B
  // total ~58.1 KB -> 2 blocks/CU

  const int tid = threadIdx.x;
  const int n   = blockIdx.x;
  const int b   = n / 49;
  const int r49 = n - b*49;
  const int ohi = r49 / 7;
  const int owi = r49 - ohi*7;

  const float* xw = x + ((size_t)b*16 + (size_t)(ohi*2))*16*544 + (size_t)(owi*2)*544;

  const int c  = tid & 31;    // sweep layout: c in-wave (softmax over c)
  const int ks = tid >> 5;    // k-group 0..15
  const int w  = tid >> 6;    // wave 0..7
  const int cc = tid >> 4;    // stats layout: one thread per (cc, pp)
  const int pp = tid & 15;

  // ---- stage poses (xor-swizzled groups) ----
  for (int idx = tid; idx < KK*PS/4; idx += NTH) {   // 1152 float4s
    const int sp  = idx >> 7;
    const int ch4 = idx & 127;
    const int kh = sp/3, kw = sp - kh*3;
    const float4 v = ld4(&xw[kh*(16*544) + kw*544 + ch4*4]);
    const int k = sp*32 + (ch4 >> 2);
    const int g = ch4 & 3;
    *(float4*)&sP[(k<<4) + ((g ^ ((k>>1)&3))<<2)] = v;
  }
  // ---- stage activations ----
  if (tid < KK/4) {
    const int sp  = tid >> 3;
    const int bc4 = tid & 7;
    const int kh = sp/3, kw = sp - kh*3;
    const float4 v = ld4(&xw[kh*(16*544) + kw*544 + 512 + bc4*4]);
    *(float4*)&sA[sp*32 + bc4*4] = v;
  }
  __syncthreads();
  if (tid < KK) { const float a = sA[tid]; sA[tid] = a * rcpf(a + EPSF); }
  __syncthreads();

  float t0, t1[PS], t2[PS];

  // ---- stats phase (R6-proven): fold ks-pairs, reduce 8 wave partials ----
  auto stats = [&](){
    t0 += __shfl_xor(t0, 32);
#pragma unroll
    for (int p = 0; p < PS; ++p) {
      t1[p] += __shfl_xor(t1[p], 32);
      t2[p] += __shfl_xor(t2[p], 32);
    }
    if ((tid & 32) == 0) {
      float* pr = &sPart[(w*CC + c)*33];
      pr[0] = t0;
#pragma unroll
      for (int p = 0; p < PS; ++p) { pr[1+p] = t1[p]; pr[17+p] = t2[p]; }
    }
    __syncthreads();
    {
      float T0 = 0.f, T1 = 0.f, T2 = 0.f;
#pragma unroll
      for (int j = 0; j < 8; ++j) {
        const float* pr = &sPart[(j*CC + cc)*33];
        T0 += pr[0]; T1 += pr[1+pp]; T2 += pr[17+pp];
      }
      const float z   = rcpf(T0 + EPSF);
      const float mu  = T1 * z;
      const float s0  = T0 * z;
      const float var = fmaxf(T2*z - mu*mu*(2.f - s0), 0.f) + EPSF;
      sMu[cc*17 + pp]  = mu;
      sNI2[cc*17 + pp] = -0.5f * rcpf(var);
      float lsum = 0.5f * __logf(var);
      lsum += __shfl_xor(lsum, 1);  lsum += __shfl_xor(lsum, 2);
      lsum += __shfl_xor(lsum, 4);  lsum += __shfl_xor(lsum, 8);
      if (pp == 0) {
        const float cost = (16.f*beta_u[cc] + lsum) * T0;   // r_sum = T0
        const float ao = rcpf(1.f + __expf(-(LAMF*(beta_a[cc] - cost))));
        sAo[cc] = ao; sLnA[cc] = __logf(ao); sLs[cc] = lsum;
      }
    }
    __syncthreads();
  };

  // ---- sweep 0 (it=0): r uniform -> rr = f/32 (no softmax chain; as R6) ----
  t0 = 0.f;
#pragma unroll
  for (int p = 0; p < PS; ++p) { t1[p] = 0.f; t2[p] = 0.f; }
  for (int kt = 0; kt < KT; ++kt) {
    const int k = kt*16 + ks;
    const float4* wg = (const float4*)(wgt + (((size_t)(k*32 + c)) << 4));
    const float4 w0 = wg[0], w1 = wg[1], w2 = wg[2], w3 = wg[3];
    const int sw = (k>>1)&3;
    const float* pb = &sP[k<<4];
    const float4 Pi[4] = { ld4(pb + ((0^sw)<<2)), ld4(pb + ((1^sw)<<2)),
                           ld4(pb + ((2^sw)<<2)), ld4(pb + ((3^sw)<<2)) };
    const float rr = sA[k] * (1.0f/32.0f);
    t0 += rr;
#pragma unroll
    for (int i = 0; i < 4; ++i) {
      float v0 = Pi[i].x*w0.x; v0 = fmaf(Pi[i].y, w1.x, v0); v0 = fmaf(Pi[i].z, w2.x, v0); v0 = fmaf(Pi[i].w, w3.x, v0);
      float v1 = Pi[i].x*w0.y; v1 = fmaf(Pi[i].y, w1.y, v1); v1 = fmaf(Pi[i].z, w2.y, v1); v1 = fmaf(Pi[i].w, w3.y, v1);
      float v2 = Pi[i].x*w0.z; v2 = fmaf(Pi[i].y, w1.z, v2); v2 = fmaf(Pi[i].z, w2.z, v2); v2 = fmaf(Pi[i].w, w3.z, v2);
      float v3 = Pi[i].x*w0.w; v3 = fmaf(Pi[i].y, w1.w, v3); v3 = fmaf(Pi[i].z, w2.w, v3); v3 = fmaf(Pi[i].w, w3.w, v3);
      const float m0 = rr*v0, m1 = rr*v1, m2 = rr*v2, m3 = rr*v3;
      t1[i*4+0] += m0; t2[i*4+0] = fmaf(m0, v0, t2[i*4+0]);
      t1[i*4+1] += m1; t2[i*4+1] = fmaf(m1, v1, t2[i*4+1]);
      t1[i*4+2] += m2; t2[i*4+2] = fmaf(m2, v2, t2[i*4+2]);
      t1[i*4+3] += m3; t2[i*4+3] = fmaf(m3, v3, t2[i*4+3]);
    }
  }
  stats();

  // ---- sweeps 1,2: two k-iterations interleaved (kA, kB = kA+16) ----
  for (int it = 1; it < 3; ++it) {
    float mu[PS], ni2[PS];
#pragma unroll
    for (int p = 0; p < PS; ++p) { mu[p] = sMu[c*17+p]; ni2[p] = sNI2[c*17+p]; }
    const float lc = sLnA[c] - sLs[c] - 16.f*HL2PI;
    t0 = 0.f;
#pragma unroll
    for (int p = 0; p < PS; ++p) { t1[p] = 0.f; t2[p] = 0.f; }
    for (int kt = 0; kt < KT; kt += 2) {
      const int kA = kt*16 + ks;
      const int kB = kA + 16;
      const float4* wgA = (const float4*)(wgt + (((size_t)(kA*32 + c)) << 4));
      const float4* wgB = (const float4*)(wgt + (((size_t)(kB*32 + c)) << 4));
      const float4 a0 = wgA[0], a1 = wgA[1], a2 = wgA[2], a3 = wgA[3];
      const float4 b0 = wgB[0], b1 = wgB[1], b2 = wgB[2], b3 = wgB[3];
      const int swA = (kA>>1)&3, swB = (kB>>1)&3;
      const float* pbA = &sP[kA<<4];
      const float* pbB = &sP[kB<<4];
      const float4 PA[4] = { ld4(pbA + ((0^swA)<<2)), ld4(pbA + ((1^swA)<<2)),
                             ld4(pbA + ((2^swA)<<2)), ld4(pbA + ((3^swA)<<2)) };
      const float4 PB[4] = { ld4(pbB + ((0^swB)<<2)), ld4(pbB + ((1^swB)<<2)),
                             ld4(pbB + ((2^swB)<<2)), ld4(pbB + ((3^swB)<<2)) };
      float vA[PS], vB[PS];
#pragma unroll
      for (int i = 0; i < 4; ++i) {
        float v0 = PA[i].x*a0.x; v0 = fmaf(PA[i].y, a1.x, v0); v0 = fmaf(PA[i].z, a2.x, v0); v0 = fmaf(PA[i].w, a3.x, v0);
        float v1 = PA[i].x*a0.y; v1 = fmaf(PA[i].y, a1.y, v1); v1 = fmaf(PA[i].z, a2.y, v1); v1 = fmaf(PA[i].w, a3.y, v1);
        float v2 = PA[i].x*a0.z; v2 = fmaf(PA[i].y, a1.z, v2); v2 = fmaf(PA[i].z, a2.z, v2); v2 = fmaf(PA[i].w, a3.z, v2);
        float v3 = PA[i].x*a0.w; v3 = fmaf(PA[i].y, a1.w, v3); v3 = fmaf(PA[i].z, a2.w, v3); v3 = fmaf(PA[i].w, a3.w, v3);
        vA[i*4+0] = v0; vA[i*4+1] = v1; vA[i*4+2] = v2; vA[i*4+3] = v3;
      }
#pragma unroll
      for (int i = 0; i < 4; ++i) {
        float v0 = PB[i].x*b0.x; v0 = fmaf(PB[i].y, b1.x, v0); v0 = fmaf(PB[i].z, b2.x, v0); v0 = fmaf(PB[i].w, b3.x, v0);
        float v1 = PB[i].x*b0.y; v1 = fmaf(PB[i].y, b1.y, v1); v1 = fmaf(PB[i].z, b2.y, v1); v1 = fmaf(PB[i].w, b3.y, v1);
        float v2 = PB[i].x*b0.z; v2 = fmaf(PB[i].y, b1.z, v2); v2 = fmaf(PB[i].z, b2.z, v2); v2 = fmaf(PB[i].w, b3.z, v2);
        float v3 = PB[i].x*b0.w; v3 = fmaf(PB[i].y, b1.w, v3); v3 = fmaf(PB[i].z, b2.w, v3); v3 = fmaf(PB[i].w, b3.w, v3);
        vB[i*4+0] = v0; vB[i*4+1] = v1; vB[i*4+2] = v2; vB[i*4+3] = v3;
      }
      float accA = 0.f, accB = 0.f;
#pragma unroll
      for (int p = 0; p < PS; ++p) {
        const float dA = vA[p] - mu[p];
        const float dB = vB[p] - mu[p];
        accA = fmaf(dA*dA, ni2[p], accA);
        accB = fmaf(dB*dB, ni2[p], accB);
      }
      const float lnA = accA + lc, lnB = accB + lc;
      // interleaved softmax chains over c (independent -> co-scheduled)
      float mA = lnA, mB = lnB;
      mA = fmaxf(mA, __shfl_xor(mA, 1));  mB = fmaxf(mB, __shfl_xor(mB, 1));
      mA = fmaxf(mA, __shfl_xor(mA, 2));  mB = fmaxf(mB, __shfl_xor(mB, 2));
      mA = fmaxf(mA, __shfl_xor(mA, 4));  mB = fmaxf(mB, __shfl_xor(mB, 4));
      mA = fmaxf(mA, __shfl_xor(mA, 8));  mB = fmaxf(mB, __shfl_xor(mB, 8));
      mA = fmaxf(mA, __shfl_xor(mA, 16)); mB = fmaxf(mB, __shfl_xor(mB, 16));
      const float eA = __expf(lnA - mA);
      const float eB = __expf(lnB - mB);
      float uA = eA, uB = eB;
      uA += __shfl_xor(uA, 1);  uB += __shfl_xor(uB, 1);
      uA += __shfl_xor(uA, 2);  uB += __shfl_xor(uB, 2);
      uA += __shfl_xor(uA, 4);  uB += __shfl_xor(uB, 4);
      uA += __shfl_xor(uA, 8);  uB += __shfl_xor(uB, 8);
      uA += __shfl_xor(uA, 16); uB += __shfl_xor(uB, 16);
      const float rrA = eA * rcpf(uA) * sA[kA];   // r * a/(a+eps)
      const float rrB = eB * rcpf(uB) * sA[kB];
      t0 += rrA + rrB;
#pragma unroll
      for (int p = 0; p < PS; ++p) {
        const float tA = rrA * vA[p];
        const float tB = rrB * vB[p];
        t1[p] += tA;
        t2[p] = fmaf(tA, vA[p], t2[p]);
        t1[p] += tB;
        t2[p] = fmaf(tB, vB[p], t2[p]);
      }
    }
    stats();
  }

  // ---- epilogue ----
  out[(size_t)n*544 + tid] = sMu[(tid>>4)*17 + (tid&15)];
  if (tid < CC) out[(size_t)n*544 + 512 + tid] = sAo[tid];
}

extern "C" void kernel_launch(void* const* d_in, const int* in_sizes, int n_in,
                              void* d_out, int out_size, void* d_ws, size_t ws_size,
                              hipStream_t stream) {
  (void)in_sizes; (void)n_in; (void)d_ws; (void)ws_size; (void)out_size;
  const float* x  = (const float*)d_in[0];
  const float* w  = (const float*)d_in[1];
  const float* ba = (const float*)d_in[2];
  const float* bu = (const float*)d_in[3];
  float* out = (float*)d_out;
  convcaps_em_kernel<<<dim3(392), dim3(NTH), 0, stream>>>(x, w, ba, bu, out);
}

// Round 9
// 147.481 us; speedup vs baseline: 1.6438x; 1.6438x over previous
//
#include <hip/hip_runtime.h>
#include <math.h>

// ConvCaps EM routing, fp32 I/O. n=392 positions, one 512-thread block each.
// R9 = R6 (proven 113us) + softmax max-chain elimination: per-sweep constant
// shift M = max_c(lc) replaces the per-k 5-shuffle max reduction (softmax is
// shift-invariant; acc<=0 guarantees no overflow; underflow guarded by
// s+1e-37). Saves 5 dependent ds_swizzle + 5 fmax per k-iteration.
// NOTE (R3/R8 lesson): never pass a min-waves arg to __launch_bounds__ on
// this toolchain — it allocates ~half the expected VGPR budget and spills
// ((512,4)->64 VGPR + 152MB scratch writes; (1024,8)->32 VGPR + 838MB).

#define NTH 512
#define KK 288
#define KT 18         // 288 / 16 k-groups
#define CC 32
#define PS 16
#define EPSF 1e-8f
#define LAMF 1e-3f
#define HL2PI 0.91893853320467274178f   // 0.5*ln(2*pi)

__device__ __forceinline__ float4 ld4(const float* p){ return *(const float4*)p; }
__device__ __forceinline__ float rcpf(float x){ return __builtin_amdgcn_rcpf(x); }

extern "C" __global__ void __launch_bounds__(NTH)
convcaps_em_kernel(const float* __restrict__ x, const float* __restrict__ wgt,
                   const float* __restrict__ beta_a, const float* __restrict__ beta_u,
                   float* __restrict__ out)
{
  __shared__ float sP[KK*PS];        // poses, xor-swizzled groups (18432 B)
  __shared__ float sA[KK];           // f = a/(a+eps) (1152 B)
  __shared__ float sPart[8*CC*33];   // wave partials t0|t1[16]|t2[16] (33792 B)
  __shared__ float sMu[CC*17];       // (2176 B)
  __shared__ float sNI2[CC*17];      // -0.5/sigma^2 (2176 B)
  __shared__ float sLs[CC], sLnA[CC], sAo[CC];   // 384 B
  // total ~58.1 KB -> 2 blocks/CU

  const int tid = threadIdx.x;
  const int n   = blockIdx.x;
  const int b   = n / 49;
  const int r49 = n - b*49;
  const int ohi = r49 / 7;
  const int owi = r49 - ohi*7;

  const float* xw = x + ((size_t)b*16 + (size_t)(ohi*2))*16*544 + (size_t)(owi*2)*544;

  const int c  = tid & 31;    // sweep layout: c in-wave (softmax over c)
  const int ks = tid >> 5;    // k-group 0..15
  const int w  = tid >> 6;    // wave 0..7
  const int cc = tid >> 4;    // stats layout: one thread per (cc, pp)
  const int pp = tid & 15;

  // ---- stage poses (xor-swizzled groups) ----
  for (int idx = tid; idx < KK*PS/4; idx += NTH) {   // 1152 float4s
    const int sp  = idx >> 7;
    const int ch4 = idx & 127;
    const int kh = sp/3, kw = sp - kh*3;
    const float4 v = ld4(&xw[kh*(16*544) + kw*544 + ch4*4]);
    const int k = sp*32 + (ch4 >> 2);
    const int g = ch4 & 3;
    *(float4*)&sP[(k<<4) + ((g ^ ((k>>1)&3))<<2)] = v;
  }
  // ---- stage activations ----
  if (tid < KK/4) {
    const int sp  = tid >> 3;
    const int bc4 = tid & 7;
    const int kh = sp/3, kw = sp - kh*3;
    const float4 v = ld4(&xw[kh*(16*544) + kw*544 + 512 + bc4*4]);
    *(float4*)&sA[sp*32 + bc4*4] = v;
  }
  __syncthreads();
  if (tid < KK) { const float a = sA[tid]; sA[tid] = a * rcpf(a + EPSF); }
  __syncthreads();

  float t0, t1[PS], t2[PS];

  // ---- stats phase (R6-proven): fold ks-pairs, reduce 8 wave partials ----
  auto stats = [&](){
    t0 += __shfl_xor(t0, 32);
#pragma unroll
    for (int p = 0; p < PS; ++p) {
      t1[p] += __shfl_xor(t1[p], 32);
      t2[p] += __shfl_xor(t2[p], 32);
    }
    if ((tid & 32) == 0) {
      float* pr = &sPart[(w*CC + c)*33];
      pr[0] = t0;
#pragma unroll
      for (int p = 0; p < PS; ++p) { pr[1+p] = t1[p]; pr[17+p] = t2[p]; }
    }
    __syncthreads();
    {
      float T0 = 0.f, T1 = 0.f, T2 = 0.f;
#pragma unroll
      for (int j = 0; j < 8; ++j) {
        const float* pr = &sPart[(j*CC + cc)*33];
        T0 += pr[0]; T1 += pr[1+pp]; T2 += pr[17+pp];
      }
      const float z   = rcpf(T0 + EPSF);
      const float mu  = T1 * z;
      const float s0  = T0 * z;
      const float var = fmaxf(T2*z - mu*mu*(2.f - s0), 0.f) + EPSF;
      sMu[cc*17 + pp]  = mu;
      sNI2[cc*17 + pp] = -0.5f * rcpf(var);
      float lsum = 0.5f * __logf(var);
      lsum += __shfl_xor(lsum, 1);  lsum += __shfl_xor(lsum, 2);
      lsum += __shfl_xor(lsum, 4);  lsum += __shfl_xor(lsum, 8);
      if (pp == 0) {
        const float cost = (16.f*beta_u[cc] + lsum) * T0;   // r_sum = T0
        const float ao = rcpf(1.f + __expf(-(LAMF*(beta_a[cc] - cost))));
        sAo[cc] = ao; sLnA[cc] = __logf(ao); sLs[cc] = lsum;
      }
    }
    __syncthreads();
  };

  // ---- sweep 0 (it=0): r uniform -> rr = f/32 ----
  t0 = 0.f;
#pragma unroll
  for (int p = 0; p < PS; ++p) { t1[p] = 0.f; t2[p] = 0.f; }
  for (int kt = 0; kt < KT; ++kt) {
    const int k = kt*16 + ks;
    const float4* wg = (const float4*)(wgt + (((size_t)(k*32 + c)) << 4));
    const float4 w0 = wg[0], w1 = wg[1], w2 = wg[2], w3 = wg[3];
    const int sw = (k>>1)&3;
    const float* pb = &sP[k<<4];
    const float4 Pi[4] = { ld4(pb + ((0^sw)<<2)), ld4(pb + ((1^sw)<<2)),
                           ld4(pb + ((2^sw)<<2)), ld4(pb + ((3^sw)<<2)) };
    const float rr = sA[k] * (1.0f/32.0f);
    t0 += rr;
#pragma unroll
    for (int i = 0; i < 4; ++i) {
      float v0 = Pi[i].x*w0.x; v0 = fmaf(Pi[i].y, w1.x, v0); v0 = fmaf(Pi[i].z, w2.x, v0); v0 = fmaf(Pi[i].w, w3.x, v0);
      float v1 = Pi[i].x*w0.y; v1 = fmaf(Pi[i].y, w1.y, v1); v1 = fmaf(Pi[i].z, w2.y, v1); v1 = fmaf(Pi[i].w, w3.y, v1);
      float v2 = Pi[i].x*w0.z; v2 = fmaf(Pi[i].y, w1.z, v2); v2 = fmaf(Pi[i].z, w2.z, v2); v2 = fmaf(Pi[i].w, w3.z, v2);
      float v3 = Pi[i].x*w0.w; v3 = fmaf(Pi[i].y, w1.w, v3); v3 = fmaf(Pi[i].z, w2.w, v3); v3 = fmaf(Pi[i].w, w3.w, v3);
      const float m0 = rr*v0, m1 = rr*v1, m2 = rr*v2, m3 = rr*v3;
      t1[i*4+0] += m0; t2[i*4+0] = fmaf(m0, v0, t2[i*4+0]);
      t1[i*4+1] += m1; t2[i*4+1] = fmaf(m1, v1, t2[i*4+1]);
      t1[i*4+2] += m2; t2[i*4+2] = fmaf(m2, v2, t2[i*4+2]);
      t1[i*4+3] += m3; t2[i*4+3] = fmaf(m3, v3, t2[i*4+3]);
    }
  }
  stats();

  // ---- sweeps 1,2: ln_p -> shifted softmax over c (no per-k max chain) ----
  for (int it = 1; it < 3; ++it) {
    float mu[PS], ni2[PS];
#pragma unroll
    for (int p = 0; p < PS; ++p) { mu[p] = sMu[c*17+p]; ni2[p] = sNI2[c*17+p]; }
    // lc with per-sweep shift: M = max_c(lc); acc<=0 => lnap-M <= 0, no overflow
    float lcv = sLnA[c] - sLs[c] - 16.f*HL2PI;
    float M = lcv;
    M = fmaxf(M, __shfl_xor(M, 1));  M = fmaxf(M, __shfl_xor(M, 2));
    M = fmaxf(M, __shfl_xor(M, 4));  M = fmaxf(M, __shfl_xor(M, 8));
    M = fmaxf(M, __shfl_xor(M, 16));
    const float lc = lcv - M;
    t0 = 0.f;
#pragma unroll
    for (int p = 0; p < PS; ++p) { t1[p] = 0.f; t2[p] = 0.f; }
    for (int kt = 0; kt < KT; ++kt) {
      const int k = kt*16 + ks;
      const float4* wg = (const float4*)(wgt + (((size_t)(k*32 + c)) << 4));
      const float4 w0 = wg[0], w1 = wg[1], w2 = wg[2], w3 = wg[3];
      const int sw = (k>>1)&3;
      const float* pb = &sP[k<<4];
      const float4 Pi[4] = { ld4(pb + ((0^sw)<<2)), ld4(pb + ((1^sw)<<2)),
                             ld4(pb + ((2^sw)<<2)), ld4(pb + ((3^sw)<<2)) };
      float v[PS];
#pragma unroll
      for (int i = 0; i < 4; ++i) {
        float v0 = Pi[i].x*w0.x; v0 = fmaf(Pi[i].y, w1.x, v0); v0 = fmaf(Pi[i].z, w2.x, v0); v0 = fmaf(Pi[i].w, w3.x, v0);
        float v1 = Pi[i].x*w0.y; v1 = fmaf(Pi[i].y, w1.y, v1); v1 = fmaf(Pi[i].z, w2.y, v1); v1 = fmaf(Pi[i].w, w3.y, v1);
        float v2 = Pi[i].x*w0.z; v2 = fmaf(Pi[i].y, w1.z, v2); v2 = fmaf(Pi[i].z, w2.z, v2); v2 = fmaf(Pi[i].w, w3.z, v2);
        float v3 = Pi[i].x*w0.w; v3 = fmaf(Pi[i].y, w1.w, v3); v3 = fmaf(Pi[i].z, w2.w, v3); v3 = fmaf(Pi[i].w, w3.w, v3);
        v[i*4+0] = v0; v[i*4+1] = v1; v[i*4+2] = v2; v[i*4+3] = v3;
      }
      float acc = 0.f;
#pragma unroll
      for (int p = 0; p < PS; ++p) {
        const float d = v[p] - mu[p];
        acc = fmaf(d*d, ni2[p], acc);
      }
      // shifted softmax over c: exp first (safe), then one 5-shuffle sum chain
      const float e = __expf(acc + lc);
      float s = e;
      s += __shfl_xor(s, 1);  s += __shfl_xor(s, 2);  s += __shfl_xor(s, 4);
      s += __shfl_xor(s, 8);  s += __shfl_xor(s, 16);
      const float rr = e * rcpf(s + 1e-37f) * sA[k];   // r * a/(a+eps)
      t0 += rr;
#pragma unroll
      for (int p = 0; p < PS; ++p) {
        const float tmp = rr * v[p];
        t1[p] += tmp;
        t2[p] = fmaf(tmp, v[p], t2[p]);
      }
    }
    stats();
  }

  // ---- epilogue ----
  out[(size_t)n*544 + tid] = sMu[(tid>>4)*17 + (tid&15)];
  if (tid < CC) out[(size_t)n*544 + 512 + tid] = sAo[tid];
}

extern "C" void kernel_launch(void* const* d_in, const int* in_sizes, int n_in,
                              void* d_out, int out_size, void* d_ws, size_t ws_size,
                              hipStream_t stream) {
  (void)in_sizes; (void)n_in; (void)d_ws; (void)ws_size; (void)out_size;
  const float* x  = (const float*)d_in[0];
  const float* w  = (const float*)d_in[1];
  const float* ba = (const float*)d_in[2];
  const float* bu = (const float*)d_in[3];
  float* out = (float*)d_out;
  convcaps_em_kernel<<<dim3(392), dim3(NTH), 0, stream>>>(x, w, ba, bu, out);
}

// Round 10
// 130.975 us; speedup vs baseline: 1.8509x; 1.1260x over previous
//
#include <hip/hip_runtime.h>
#include <math.h>

// ConvCaps EM routing, fp32 I/O. n=392 positions, one 512-thread block each.
// R10 = R9 (proven 102.5us) + packed-fp32 math: hot-loop v-compute, ln_p acc,
// and moment accumulation rewritten on float2 ext-vectors so LLVM lowers to
// v_pk_fma_f32 / v_pk_mul_f32 / v_pk_add_f32 (VOP3P, 2 fp32 lanes/inst on
// gfx90a+) — ~halves VALU issue count in the 3 k-sweeps.
// NOTE (R3/R8 lesson): never pass min-waves to __launch_bounds__ here — it
// halves the VGPR budget and spills (152-838 MB scratch traffic).

#define NTH 512
#define KK 288
#define KT 18         // 288 / 16 k-groups
#define CC 32
#define PS 16
#define EPSF 1e-8f
#define LAMF 1e-3f
#define HL2PI 0.91893853320467274178f   // 0.5*ln(2*pi)

typedef float v2f __attribute__((ext_vector_type(2)));

__device__ __forceinline__ float4 ld4(const float* p){ return *(const float4*)p; }
__device__ __forceinline__ float rcpf(float x){ return __builtin_amdgcn_rcpf(x); }
__device__ __forceinline__ v2f bc2(float s){ return (v2f){s, s}; }
__device__ __forceinline__ v2f fma2(v2f a, v2f b, v2f c){ return __builtin_elementwise_fma(a, b, c); }

extern "C" __global__ void __launch_bounds__(NTH)
convcaps_em_kernel(const float* __restrict__ x, const float* __restrict__ wgt,
                   const float* __restrict__ beta_a, const float* __restrict__ beta_u,
                   float* __restrict__ out)
{
  __shared__ float sP[KK*PS];        // poses, xor-swizzled groups (18432 B)
  __shared__ float sA[KK];           // f = a/(a+eps) (1152 B)
  __shared__ float sPart[8*CC*33];   // wave partials t0|t1[16]|t2[16] (33792 B)
  __shared__ float sMu[CC*17];       // (2176 B)
  __shared__ float sNI2[CC*17];      // -0.5/sigma^2 (2176 B)
  __shared__ float sLs[CC], sLnA[CC], sAo[CC];   // 384 B
  // total ~58.1 KB -> 2 blocks/CU

  const int tid = threadIdx.x;
  const int n   = blockIdx.x;
  const int b   = n / 49;
  const int r49 = n - b*49;
  const int ohi = r49 / 7;
  const int owi = r49 - ohi*7;

  const float* xw = x + ((size_t)b*16 + (size_t)(ohi*2))*16*544 + (size_t)(owi*2)*544;

  const int c  = tid & 31;    // sweep layout: c in-wave (softmax over c)
  const int ks = tid >> 5;    // k-group 0..15
  const int w  = tid >> 6;    // wave 0..7
  const int cc = tid >> 4;    // stats layout: one thread per (cc, pp)
  const int pp = tid & 15;

  // ---- stage poses (xor-swizzled groups) ----
  for (int idx = tid; idx < KK*PS/4; idx += NTH) {   // 1152 float4s
    const int sp  = idx >> 7;
    const int ch4 = idx & 127;
    const int kh = sp/3, kw = sp - kh*3;
    const float4 v = ld4(&xw[kh*(16*544) + kw*544 + ch4*4]);
    const int k = sp*32 + (ch4 >> 2);
    const int g = ch4 & 3;
    *(float4*)&sP[(k<<4) + ((g ^ ((k>>1)&3))<<2)] = v;
  }
  // ---- stage activations ----
  if (tid < KK/4) {
    const int sp  = tid >> 3;
    const int bc4 = tid & 7;
    const int kh = sp/3, kw = sp - kh*3;
    const float4 v = ld4(&xw[kh*(16*544) + kw*544 + 512 + bc4*4]);
    *(float4*)&sA[sp*32 + bc4*4] = v;
  }
  __syncthreads();
  if (tid < KK) { const float a = sA[tid]; sA[tid] = a * rcpf(a + EPSF); }
  __syncthreads();

  float t0;
  v2f t1[8], t2[8];    // packed moment accumulators (pairs of pose elems)

  // ---- stats phase (R6-proven layout; unpack pairs at store) ----
  auto stats = [&](){
    t0 += __shfl_xor(t0, 32);
#pragma unroll
    for (int q = 0; q < 8; ++q) {
      t1[q].x += __shfl_xor(t1[q].x, 32);
      t1[q].y += __shfl_xor(t1[q].y, 32);
      t2[q].x += __shfl_xor(t2[q].x, 32);
      t2[q].y += __shfl_xor(t2[q].y, 32);
    }
    if ((tid & 32) == 0) {
      float* pr = &sPart[(w*CC + c)*33];
      pr[0] = t0;
#pragma unroll
      for (int q = 0; q < 8; ++q) {
        pr[1 + 2*q]     = t1[q].x;  pr[1 + 2*q + 1]  = t1[q].y;
        pr[17 + 2*q]    = t2[q].x;  pr[17 + 2*q + 1] = t2[q].y;
      }
    }
    __syncthreads();
    {
      float T0 = 0.f, T1 = 0.f, T2 = 0.f;
#pragma unroll
      for (int j = 0; j < 8; ++j) {
        const float* pr = &sPart[(j*CC + cc)*33];
        T0 += pr[0]; T1 += pr[1+pp]; T2 += pr[17+pp];
      }
      const float z   = rcpf(T0 + EPSF);
      const float mu  = T1 * z;
      const float s0  = T0 * z;
      const float var = fmaxf(T2*z - mu*mu*(2.f - s0), 0.f) + EPSF;
      sMu[cc*17 + pp]  = mu;
      sNI2[cc*17 + pp] = -0.5f * rcpf(var);
      float lsum = 0.5f * __logf(var);
      lsum += __shfl_xor(lsum, 1);  lsum += __shfl_xor(lsum, 2);
      lsum += __shfl_xor(lsum, 4);  lsum += __shfl_xor(lsum, 8);
      if (pp == 0) {
        const float cost = (16.f*beta_u[cc] + lsum) * T0;   // r_sum = T0
        const float ao = rcpf(1.f + __expf(-(LAMF*(beta_a[cc] - cost))));
        sAo[cc] = ao; sLnA[cc] = __logf(ao); sLs[cc] = lsum;
      }
    }
    __syncthreads();
  };

  // ---- packed v-compute: rows i=0..3, pairs lo(l=0,1)/hi(l=2,3) ----
  // W rows wj = wgt row j as float4 {l0,l1,l2,l3}
  // v[i*2]   = P[i][0]*w0.lo + P[i][1]*w1.lo + P[i][2]*w2.lo + P[i][3]*w3.lo
  // v[i*2+1] = same with .hi

  // ---- sweep 0 (it=0): r uniform -> rr = f/32 ----
  t0 = 0.f;
#pragma unroll
  for (int q = 0; q < 8; ++q) { t1[q] = bc2(0.f); t2[q] = bc2(0.f); }
  for (int kt = 0; kt < KT; ++kt) {
    const int k = kt*16 + ks;
    const float4* wg = (const float4*)(wgt + (((size_t)(k*32 + c)) << 4));
    const float4 w0 = wg[0], w1 = wg[1], w2 = wg[2], w3 = wg[3];
    const v2f w0lo = {w0.x,w0.y}, w0hi = {w0.z,w0.w};
    const v2f w1lo = {w1.x,w1.y}, w1hi = {w1.z,w1.w};
    const v2f w2lo = {w2.x,w2.y}, w2hi = {w2.z,w2.w};
    const v2f w3lo = {w3.x,w3.y}, w3hi = {w3.z,w3.w};
    const int sw = (k>>1)&3;
    const float* pb = &sP[k<<4];
    const float4 Pi[4] = { ld4(pb + ((0^sw)<<2)), ld4(pb + ((1^sw)<<2)),
                           ld4(pb + ((2^sw)<<2)), ld4(pb + ((3^sw)<<2)) };
    const float rr = sA[k] * (1.0f/32.0f);
    t0 += rr;
    const v2f rr2 = bc2(rr);
#pragma unroll
    for (int i = 0; i < 4; ++i) {
      v2f lo = bc2(Pi[i].x) * w0lo;
      lo = fma2(bc2(Pi[i].y), w1lo, lo);
      lo = fma2(bc2(Pi[i].z), w2lo, lo);
      lo = fma2(bc2(Pi[i].w), w3lo, lo);
      v2f hi = bc2(Pi[i].x) * w0hi;
      hi = fma2(bc2(Pi[i].y), w1hi, hi);
      hi = fma2(bc2(Pi[i].z), w2hi, hi);
      hi = fma2(bc2(Pi[i].w), w3hi, hi);
      const v2f mlo = rr2 * lo, mhi = rr2 * hi;
      t1[i*2]   += mlo;  t2[i*2]   = fma2(mlo, lo, t2[i*2]);
      t1[i*2+1] += mhi;  t2[i*2+1] = fma2(mhi, hi, t2[i*2+1]);
    }
  }
  stats();

  // ---- sweeps 1,2: ln_p -> shifted softmax over c (R9) with packed math ----
  for (int it = 1; it < 3; ++it) {
    v2f mu2[8], ni22[8];
#pragma unroll
    for (int q = 0; q < 8; ++q) {
      mu2[q]  = (v2f){ sMu[c*17 + 2*q],  sMu[c*17 + 2*q + 1] };
      ni22[q] = (v2f){ sNI2[c*17 + 2*q], sNI2[c*17 + 2*q + 1] };
    }
    float lcv = sLnA[c] - sLs[c] - 16.f*HL2PI;
    float M = lcv;
    M = fmaxf(M, __shfl_xor(M, 1));  M = fmaxf(M, __shfl_xor(M, 2));
    M = fmaxf(M, __shfl_xor(M, 4));  M = fmaxf(M, __shfl_xor(M, 8));
    M = fmaxf(M, __shfl_xor(M, 16));
    const float lc = lcv - M;
    t0 = 0.f;
#pragma unroll
    for (int q = 0; q < 8; ++q) { t1[q] = bc2(0.f); t2[q] = bc2(0.f); }
    for (int kt = 0; kt < KT; ++kt) {
      const int k = kt*16 + ks;
      const float4* wg = (const float4*)(wgt + (((size_t)(k*32 + c)) << 4));
      const float4 w0 = wg[0], w1 = wg[1], w2 = wg[2], w3 = wg[3];
      const v2f w0lo = {w0.x,w0.y}, w0hi = {w0.z,w0.w};
      const v2f w1lo = {w1.x,w1.y}, w1hi = {w1.z,w1.w};
      const v2f w2lo = {w2.x,w2.y}, w2hi = {w2.z,w2.w};
      const v2f w3lo = {w3.x,w3.y}, w3hi = {w3.z,w3.w};
      const int sw = (k>>1)&3;
      const float* pb = &sP[k<<4];
      const float4 Pi[4] = { ld4(pb + ((0^sw)<<2)), ld4(pb + ((1^sw)<<2)),
                             ld4(pb + ((2^sw)<<2)), ld4(pb + ((3^sw)<<2)) };
      v2f v[8];
#pragma unroll
      for (int i = 0; i < 4; ++i) {
        v2f lo = bc2(Pi[i].x) * w0lo;
        lo = fma2(bc2(Pi[i].y), w1lo, lo);
        lo = fma2(bc2(Pi[i].z), w2lo, lo);
        lo = fma2(bc2(Pi[i].w), w3lo, lo);
        v2f hi = bc2(Pi[i].x) * w0hi;
        hi = fma2(bc2(Pi[i].y), w1hi, hi);
        hi = fma2(bc2(Pi[i].z), w2hi, hi);
        hi = fma2(bc2(Pi[i].w), w3hi, hi);
        v[i*2] = lo; v[i*2+1] = hi;
      }
      v2f acc2 = bc2(0.f);
#pragma unroll
      for (int q = 0; q < 8; ++q) {
        const v2f d = v[q] - mu2[q];
        acc2 = fma2(d*d, ni22[q], acc2);
      }
      const float acc = acc2.x + acc2.y;
      // shifted softmax over c: exp first (acc<=0, lc<=0 -> safe), 5-shuffle sum
      const float e = __expf(acc + lc);
      float s = e;
      s += __shfl_xor(s, 1);  s += __shfl_xor(s, 2);  s += __shfl_xor(s, 4);
      s += __shfl_xor(s, 8);  s += __shfl_xor(s, 16);
      const float rr = e * rcpf(s + 1e-37f) * sA[k];   // r * a/(a+eps)
      t0 += rr;
      const v2f rr2 = bc2(rr);
#pragma unroll
      for (int q = 0; q < 8; ++q) {
        const v2f tmp = rr2 * v[q];
        t1[q] += tmp;
        t2[q] = fma2(tmp, v[q], t2[q]);
      }
    }
    stats();
  }

  // ---- epilogue ----
  out[(size_t)n*544 + tid] = sMu[(tid>>4)*17 + (tid&15)];
  if (tid < CC) out[(size_t)n*544 + 512 + tid] = sAo[tid];
}

extern "C" void kernel_launch(void* const* d_in, const int* in_sizes, int n_in,
                              void* d_out, int out_size, void* d_ws, size_t ws_size,
                              hipStream_t stream) {
  (void)in_sizes; (void)n_in; (void)d_ws; (void)ws_size; (void)out_size;
  const float* x  = (const float*)d_in[0];
  const float* w  = (const float*)d_in[1];
  const float* ba = (const float*)d_in[2];
  const float* bu = (const float*)d_in[3];
  float* out = (float*)d_out;
  convcaps_em_kernel<<<dim3(392), dim3(NTH), 0, stream>>>(x, w, ba, bu, out);
}

// Round 11
// 122.622 us; speedup vs baseline: 1.9770x; 1.0681x over previous
//
#include <hip/hip_runtime.h>
#include <math.h>

// ConvCaps EM routing, fp32 I/O. n=392 positions, one 512-thread block each.
// R11 = R10 (proven 83us, packed fp32) + two latency attacks:
//  (a) explicit W software-pipeline: next k-iteration's 64B W tile loaded at
//      top of body, consumed next iter -> full-body L2-latency overlap.
//  (b) DPP butterflies for cross-lane reductions: v_add/v_max + DPP
//      (quad_perm xor1/xor2, row_half_mirror=xor7, row_mirror=xor15; valid
//      reduction steps at group granularity) instead of ds_swizzle (~30cyc
//      each) for all but the xor16 step.
// NOTE (R3/R8): never pass min-waves to __launch_bounds__ — halves VGPR
// budget and spills. Keep VGPR <=128 or 2-block/CU co-residency dies.

#define NTH 512
#define KK 288
#define KT 18         // 288 / 16 k-groups
#define CC 32
#define PS 16
#define EPSF 1e-8f
#define LAMF 1e-3f
#define HL2PI 0.91893853320467274178f   // 0.5*ln(2*pi)

typedef float v2f __attribute__((ext_vector_type(2)));

__device__ __forceinline__ float4 ld4(const float* p){ return *(const float4*)p; }
__device__ __forceinline__ float rcpf(float x){ return __builtin_amdgcn_rcpf(x); }
__device__ __forceinline__ v2f bc2(float s){ return (v2f){s, s}; }
__device__ __forceinline__ v2f fma2(v2f a, v2f b, v2f c){ return __builtin_elementwise_fma(a, b, c); }

// DPP cross-lane reduce steps (VALU pipe, ~2-4cyc vs ds_swizzle ~30cyc).
// 0xB1 quad_perm(1,0,3,2)=xor1 | 0x4E quad_perm(2,3,0,1)=xor2 |
// 0x141 row_half_mirror=xor7 (acts as xor4 on 4-group sums) |
// 0x140 row_mirror=xor15 (acts as xor8 on 8-group sums)
template<int CTRL>
__device__ __forceinline__ float dpp_add(float x){
  const int p = __builtin_amdgcn_update_dpp(0, __builtin_bit_cast(int, x),
                                            CTRL, 0xF, 0xF, true);
  return x + __builtin_bit_cast(float, p);
}
template<int CTRL>
__device__ __forceinline__ float dpp_max(float x){
  const int p = __builtin_amdgcn_update_dpp(0, __builtin_bit_cast(int, x),
                                            CTRL, 0xF, 0xF, true);
  return fmaxf(x, __builtin_bit_cast(float, p));
}
// sum over 32-lane group, all lanes get total
__device__ __forceinline__ float sum32(float s){
  s = dpp_add<0xB1>(s); s = dpp_add<0x4E>(s);
  s = dpp_add<0x141>(s); s = dpp_add<0x140>(s);
  s += __shfl_xor(s, 16);
  return s;
}

extern "C" __global__ void __launch_bounds__(NTH)
convcaps_em_kernel(const float* __restrict__ x, const float* __restrict__ wgt,
                   const float* __restrict__ beta_a, const float* __restrict__ beta_u,
                   float* __restrict__ out)
{
  __shared__ float sP[KK*PS];        // poses, xor-swizzled groups (18432 B)
  __shared__ float sA[KK];           // f = a/(a+eps) (1152 B)
  __shared__ float sPart[8*CC*33];   // wave partials t0|t1[16]|t2[16] (33792 B)
  __shared__ float sMu[CC*17];       // (2176 B)
  __shared__ float sNI2[CC*17];      // -0.5/sigma^2 (2176 B)
  __shared__ float sLs[CC], sLnA[CC], sAo[CC];   // 384 B
  // total ~58.1 KB -> 2 blocks/CU

  const int tid = threadIdx.x;
  const int n   = blockIdx.x;
  const int b   = n / 49;
  const int r49 = n - b*49;
  const int ohi = r49 / 7;
  const int owi = r49 - ohi*7;

  const float* xw = x + ((size_t)b*16 + (size_t)(ohi*2))*16*544 + (size_t)(owi*2)*544;

  const int c  = tid & 31;    // sweep layout: c in-wave (softmax over c)
  const int ks = tid >> 5;    // k-group 0..15
  const int w  = tid >> 6;    // wave 0..7
  const int cc = tid >> 4;    // stats layout: one thread per (cc, pp)
  const int pp = tid & 15;

  // ---- stage poses (xor-swizzled groups) ----
  for (int idx = tid; idx < KK*PS/4; idx += NTH) {   // 1152 float4s
    const int sp  = idx >> 7;
    const int ch4 = idx & 127;
    const int kh = sp/3, kw = sp - kh*3;
    const float4 v = ld4(&xw[kh*(16*544) + kw*544 + ch4*4]);
    const int k = sp*32 + (ch4 >> 2);
    const int g = ch4 & 3;
    *(float4*)&sP[(k<<4) + ((g ^ ((k>>1)&3))<<2)] = v;
  }
  // ---- stage activations ----
  if (tid < KK/4) {
    const int sp  = tid >> 3;
    const int bc4 = tid & 7;
    const int kh = sp/3, kw = sp - kh*3;
    const float4 v = ld4(&xw[kh*(16*544) + kw*544 + 512 + bc4*4]);
    *(float4*)&sA[sp*32 + bc4*4] = v;
  }
  __syncthreads();
  if (tid < KK) { const float a = sA[tid]; sA[tid] = a * rcpf(a + EPSF); }
  __syncthreads();

  float t0;
  v2f t1[8], t2[8];    // packed moment accumulators

  // ---- stats phase (R6-proven layout; unpack pairs at store) ----
  auto stats = [&](){
    t0 += __shfl_xor(t0, 32);
#pragma unroll
    for (int q = 0; q < 8; ++q) {
      t1[q].x += __shfl_xor(t1[q].x, 32);
      t1[q].y += __shfl_xor(t1[q].y, 32);
      t2[q].x += __shfl_xor(t2[q].x, 32);
      t2[q].y += __shfl_xor(t2[q].y, 32);
    }
    if ((tid & 32) == 0) {
      float* pr = &sPart[(w*CC + c)*33];
      pr[0] = t0;
#pragma unroll
      for (int q = 0; q < 8; ++q) {
        pr[1 + 2*q]     = t1[q].x;  pr[1 + 2*q + 1]  = t1[q].y;
        pr[17 + 2*q]    = t2[q].x;  pr[17 + 2*q + 1] = t2[q].y;
      }
    }
    __syncthreads();
    {
      float T0 = 0.f, T1 = 0.f, T2 = 0.f;
#pragma unroll
      for (int j = 0; j < 8; ++j) {
        const float* pr = &sPart[(j*CC + cc)*33];
        T0 += pr[0]; T1 += pr[1+pp]; T2 += pr[17+pp];
      }
      const float z   = rcpf(T0 + EPSF);
      const float mu  = T1 * z;
      const float s0  = T0 * z;
      const float var = fmaxf(T2*z - mu*mu*(2.f - s0), 0.f) + EPSF;
      sMu[cc*17 + pp]  = mu;
      sNI2[cc*17 + pp] = -0.5f * rcpf(var);
      float lsum = 0.5f * __logf(var);
      // sum over 16-lane (pp) group: xor1,2,7,15 all stay within the group
      lsum = dpp_add<0xB1>(lsum); lsum = dpp_add<0x4E>(lsum);
      lsum = dpp_add<0x141>(lsum); lsum = dpp_add<0x140>(lsum);
      if (pp == 0) {
        const float cost = (16.f*beta_u[cc] + lsum) * T0;   // r_sum = T0
        const float ao = rcpf(1.f + __expf(-(LAMF*(beta_a[cc] - cost))));
        sAo[cc] = ao; sLnA[cc] = __logf(ao); sLs[cc] = lsum;
      }
    }
    __syncthreads();
  };

  const float4* wg4 = (const float4*)wgt;

  // ---- sweep 0 (it=0): r uniform -> rr = f/32, W software-pipelined ----
  t0 = 0.f;
#pragma unroll
  for (int q = 0; q < 8; ++q) { t1[q] = bc2(0.f); t2[q] = bc2(0.f); }
  float4 cw0, cw1, cw2, cw3;
  {
    const size_t base = ((size_t)(ks*32 + c))*4;   // kt=0 -> k=ks
    cw0 = wg4[base]; cw1 = wg4[base+1]; cw2 = wg4[base+2]; cw3 = wg4[base+3];
  }
  for (int kt = 0; kt < KT; ++kt) {
    const int k = kt*16 + ks;
    const int kn = ((kt+1 < KT) ? kt+1 : kt)*16 + ks;
    float4 nw0, nw1, nw2, nw3;
    {
      const size_t base = ((size_t)(kn*32 + c))*4;
      nw0 = wg4[base]; nw1 = wg4[base+1]; nw2 = wg4[base+2]; nw3 = wg4[base+3];
    }
    const v2f w0lo = {cw0.x,cw0.y}, w0hi = {cw0.z,cw0.w};
    const v2f w1lo = {cw1.x,cw1.y}, w1hi = {cw1.z,cw1.w};
    const v2f w2lo = {cw2.x,cw2.y}, w2hi = {cw2.z,cw2.w};
    const v2f w3lo = {cw3.x,cw3.y}, w3hi = {cw3.z,cw3.w};
    const int sw = (k>>1)&3;
    const float* pb = &sP[k<<4];
    const float4 Pi[4] = { ld4(pb + ((0^sw)<<2)), ld4(pb + ((1^sw)<<2)),
                           ld4(pb + ((2^sw)<<2)), ld4(pb + ((3^sw)<<2)) };
    const float rr = sA[k] * (1.0f/32.0f);
    t0 += rr;
    const v2f rr2 = bc2(rr);
#pragma unroll
    for (int i = 0; i < 4; ++i) {
      v2f lo = bc2(Pi[i].x) * w0lo;
      lo = fma2(bc2(Pi[i].y), w1lo, lo);
      lo = fma2(bc2(Pi[i].z), w2lo, lo);
      lo = fma2(bc2(Pi[i].w), w3lo, lo);
      v2f hi = bc2(Pi[i].x) * w0hi;
      hi = fma2(bc2(Pi[i].y), w1hi, hi);
      hi = fma2(bc2(Pi[i].z), w2hi, hi);
      hi = fma2(bc2(Pi[i].w), w3hi, hi);
      const v2f mlo = rr2 * lo, mhi = rr2 * hi;
      t1[i*2]   += mlo;  t2[i*2]   = fma2(mlo, lo, t2[i*2]);
      t1[i*2+1] += mhi;  t2[i*2+1] = fma2(mhi, hi, t2[i*2+1]);
    }
    cw0 = nw0; cw1 = nw1; cw2 = nw2; cw3 = nw3;
  }
  stats();

  // ---- sweeps 1,2: ln_p -> shifted softmax over c, W software-pipelined ----
  for (int it = 1; it < 3; ++it) {
    v2f mu2[8], ni22[8];
#pragma unroll
    for (int q = 0; q < 8; ++q) {
      mu2[q]  = (v2f){ sMu[c*17 + 2*q],  sMu[c*17 + 2*q + 1] };
      ni22[q] = (v2f){ sNI2[c*17 + 2*q], sNI2[c*17 + 2*q + 1] };
    }
    float lcv = sLnA[c] - sLs[c] - 16.f*HL2PI;
    float M = lcv;
    M = dpp_max<0xB1>(M);  M = dpp_max<0x4E>(M);
    M = dpp_max<0x141>(M); M = dpp_max<0x140>(M);
    M = fmaxf(M, __shfl_xor(M, 16));
    const float lc = lcv - M;
    t0 = 0.f;
#pragma unroll
    for (int q = 0; q < 8; ++q) { t1[q] = bc2(0.f); t2[q] = bc2(0.f); }
    {
      const size_t base = ((size_t)(ks*32 + c))*4;
      cw0 = wg4[base]; cw1 = wg4[base+1]; cw2 = wg4[base+2]; cw3 = wg4[base+3];
    }
    for (int kt = 0; kt < KT; ++kt) {
      const int k = kt*16 + ks;
      const int kn = ((kt+1 < KT) ? kt+1 : kt)*16 + ks;
      float4 nw0, nw1, nw2, nw3;
      {
        const size_t base = ((size_t)(kn*32 + c))*4;
        nw0 = wg4[base]; nw1 = wg4[base+1]; nw2 = wg4[base+2]; nw3 = wg4[base+3];
      }
      const v2f w0lo = {cw0.x,cw0.y}, w0hi = {cw0.z,cw0.w};
      const v2f w1lo = {cw1.x,cw1.y}, w1hi = {cw1.z,cw1.w};
      const v2f w2lo = {cw2.x,cw2.y}, w2hi = {cw2.z,cw2.w};
      const v2f w3lo = {cw3.x,cw3.y}, w3hi = {cw3.z,cw3.w};
      const int sw = (k>>1)&3;
      const float* pb = &sP[k<<4];
      const float4 Pi[4] = { ld4(pb + ((0^sw)<<2)), ld4(pb + ((1^sw)<<2)),
                             ld4(pb + ((2^sw)<<2)), ld4(pb + ((3^sw)<<2)) };
      v2f v[8];
#pragma unroll
      for (int i = 0; i < 4; ++i) {
        v2f lo = bc2(Pi[i].x) * w0lo;
        lo = fma2(bc2(Pi[i].y), w1lo, lo);
        lo = fma2(bc2(Pi[i].z), w2lo, lo);
        lo = fma2(bc2(Pi[i].w), w3lo, lo);
        v2f hi = bc2(Pi[i].x) * w0hi;
        hi = fma2(bc2(Pi[i].y), w1hi, hi);
        hi = fma2(bc2(Pi[i].z), w2hi, hi);
        hi = fma2(bc2(Pi[i].w), w3hi, hi);
        v[i*2] = lo; v[i*2+1] = hi;
      }
      v2f acc2 = bc2(0.f);
#pragma unroll
      for (int q = 0; q < 8; ++q) {
        const v2f d = v[q] - mu2[q];
        acc2 = fma2(d*d, ni22[q], acc2);
      }
      const float acc = acc2.x + acc2.y;
      // shifted softmax over c (R9): exp first (acc<=0, lc<=0), DPP sum chain
      const float e = __expf(acc + lc);
      const float s = sum32(e);
      const float rr = e * rcpf(s + 1e-37f) * sA[k];   // r * a/(a+eps)
      t0 += rr;
      const v2f rr2 = bc2(rr);
#pragma unroll
      for (int q = 0; q < 8; ++q) {
        const v2f tmp = rr2 * v[q];
        t1[q] += tmp;
        t2[q] = fma2(tmp, v[q], t2[q]);
      }
      cw0 = nw0; cw1 = nw1; cw2 = nw2; cw3 = nw3;
    }
    stats();
  }

  // ---- epilogue ----
  out[(size_t)n*544 + tid] = sMu[(tid>>4)*17 + (tid&15)];
  if (tid < CC) out[(size_t)n*544 + 512 + tid] = sAo[tid];
}

extern "C" void kernel_launch(void* const* d_in, const int* in_sizes, int n_in,
                              void* d_out, int out_size, void* d_ws, size_t ws_size,
                              hipStream_t stream) {
  (void)in_sizes; (void)n_in; (void)d_ws; (void)ws_size; (void)out_size;
  const float* x  = (const float*)d_in[0];
  const float* w  = (const float*)d_in[1];
  const float* ba = (const float*)d_in[2];
  const float* bu = (const float*)d_in[3];
  float* out = (float*)d_out;
  convcaps_em_kernel<<<dim3(392), dim3(NTH), 0, stream>>>(x, w, ba, bu, out);
}